// Round 12
// baseline (48.573 us; speedup 1.0000x reference)
//
#include <hip/hip_runtime.h>
#include <hip/hip_bf16.h>

#define N 4096
#define D 768
#define LN2 0.69314718055994530942f
#define QSCALE 5.371583f   // sqrt(20 * log2(e)); applied to BOTH inputs -> logits in base-2 domain

typedef __attribute__((ext_vector_type(4))) int   i32x4;
typedef __attribute__((ext_vector_type(8))) int   i32x8;
typedef __attribute__((ext_vector_type(4))) float f32x4;

#define EXP2F(x) __builtin_amdgcn_exp2f(x)   // v_exp_f32: 2^x
#define LOG2F(x) __builtin_amdgcn_logf(x)    // v_log_f32: log2(x)

// global -> LDS direct DMA, 16B per lane, linear dest (wave base + lane*16)
#define GLDS16(g, l) __builtin_amdgcn_global_load_lds( \
    (const __attribute__((address_space(1))) void*)(g), \
    (__attribute__((address_space(3))) void*)(l), 16, 0, 0)

// ws layout (bytes):
//   [0,       3145728)  A fp8 e4m3 (anchors * QSCALE), N*D
//   [3145728, 6291456)  B fp8 e4m3 (positives * QSCALE), N*D
//   [6291456, 6815744)  partial[32][4096] float  (per colTile row sums of 2^s)
//   [6815744, 6832128)  diagS[4096] float        (s2_jj, base-2 logit)
//   [6832128, 6848512)  lastS[4096] float        (s2_{j,N-1})

__global__ void convert_kernel(const float* __restrict__ A, const float* __restrict__ B,
                               unsigned* __restrict__ Af8, unsigned* __restrict__ Bf8,
                               float* __restrict__ out) {
    if (blockIdx.x == 0 && threadIdx.x == 0) out[0] = 0.0f;  // rowloss atomicAdd target
    const int total = N * D / 4;
    int idx = blockIdx.x * blockDim.x + threadIdx.x;
    int stride = gridDim.x * blockDim.x;
    for (int i = idx; i < total; i += stride) {
        float4 a = ((const float4*)A)[i];
        float4 b = ((const float4*)B)[i];
        int pa = __builtin_amdgcn_cvt_pk_fp8_f32(a.x * QSCALE, a.y * QSCALE, 0, 0);
        pa     = __builtin_amdgcn_cvt_pk_fp8_f32(a.z * QSCALE, a.w * QSCALE, pa, 1);
        int pb = __builtin_amdgcn_cvt_pk_fp8_f32(b.x * QSCALE, b.y * QSCALE, 0, 0);
        pb     = __builtin_amdgcn_cvt_pk_fp8_f32(b.z * QSCALE, b.w * QSCALE, pb, 1);
        Af8[i] = (unsigned)pa;
        Bf8[i] = (unsigned)pb;
    }
}

// 128x128 tile, BK=128, 4 waves (2x2), per-wave 64x64 = acc[4][4] of
// 16x16x128 scaled-MFMA (scales = 1.0 = 0x7F E8M0).
// CHANGE vs R11 (occupancy lever): B is NOT staged in LDS — each lane loads
// its own B fragment global->reg (2 x dwordx4 per nf at col*D + {hi*16,
// hi*16+64}; lanes {lr, hi=0..3} jointly consume full 64B lines -> coalesced,
// L2-resident panels via XCD swizzle). LDS = A only, 2x16KB + 1KB = 33 KB
// -> 3-4 blocks/CU (12-16 waves) instead of 2 (8 waves): cross-block overlap
// fills the 2-phase barrier stalls (m114 mechanism; m233 says stage+barrier
// was ~72% of the 2-phase wall).
// Pipeline: depth-2 counted vmcnt on A only (4 GLDS/wave/tile): at iter top
// outstanding = A_{t+1} (B loads of iter t-1 are compiler-waited before their
// MFMAs, hence retired) -> vmcnt(4); final iter vmcnt(0). lgkmcnt(0)+barrier
// before re-staging the A buffer (rule 18). Chunk-XOR swizzle on A's global
// source AND fragment ds_read (rule 21); lane k-window {hi, hi+4} for BOTH
// A and B (k-permutation invariance keeps the dot product correct).
__global__ __launch_bounds__(256) void gemm_kernel(const unsigned char* __restrict__ Af8,
                                                   const unsigned char* __restrict__ Bf8,
                                                   float* __restrict__ partial,
                                                   float* __restrict__ diagS,
                                                   float* __restrict__ lastS) {
    __shared__ __align__(16) unsigned char As[2][128 * 128];  // 2 x 16 KB (A only)
    __shared__ float rowsum2[2][128];

    const int t    = threadIdx.x;
    // XCD-chunked bijective swizzle (1024 blocks, nwg%8==0): xcd = bid&7 owns
    // an 8x16 rectangle of the 32x32 block grid (panels ~2.3MB < 4MB L2).
    const int bid  = blockIdx.x;
    const int xcd  = bid & 7;
    const int ii   = bid >> 3;                        // 0..127
    const int bRow = ((xcd >> 1) << 3) + (ii >> 4);   // {0,8,16,24} + 0..7
    const int bCol = ((xcd & 1) << 4) + (ii & 15);    // {0,16} + 0..15
    const int lane = t & 63;
    const int w    = t >> 6;      // wave 0..3
    const int wr   = w >> 1;      // wave row 0..1
    const int wc   = w & 1;       // wave col 0..1
    const int lr   = lane & 15;
    const int hi   = lane >> 4;   // 0..3

    // A staging: thread t covers (row t>>3 of a 32-row round, 16B chunk t&7);
    // source chunk XOR-swizzled so linear LDS holds the swizzled image
    const int srow = t >> 3;            // 0..31
    const int sc   = t & 7;             // 0..7
    const int gcv  = sc ^ (srow & 7);   // swizzled global chunk
    const size_t aOff = (size_t)(bRow * 128 + srow) * D + gcv * 16;

    // B direct-load base: this lane's column and k-window start
    const unsigned char* Bbase = Bf8 + (size_t)(bCol * 128 + wc * 64 + lr) * D + hi * 16;

    f32x4 acc[4][4] = {};

    union Frag { i32x8 v; i32x4 h[2]; };

#define STAGE_A(BUF, T) do {                                                            \
    const size_t kb_ = (size_t)(T) * 128;                                               \
    _Pragma("unroll")                                                                   \
    for (int inst = 0; inst < 4; ++inst)                                                \
        GLDS16(Af8 + aOff + (size_t)inst * 32 * D + kb_, &As[BUF][inst * 4096 + w * 1024]); \
} while (0)

// A fragment: logical chunks {hi, hi+4}, physical = logical ^ (lr&7).
#define LDFRAG_A(DST, BUF, ROW) do {                                                    \
    (DST).h[0] = *(const i32x4*)&As[BUF][(ROW) * 128 + ((hi ^ (lr & 7)) * 16)];         \
    (DST).h[1] = *(const i32x4*)&As[BUF][(ROW) * 128 + (((hi + 4) ^ (lr & 7)) * 16)];   \
} while (0)

// B fragment nf: k-bytes {hi*16..+16, hi*16+64..+16} of column (wc*64+nf*16+lr)
#define LOADB(T) do {                                                                   \
    const unsigned char* bp_ = Bbase + (size_t)(T) * 128;                               \
    _Pragma("unroll")                                                                   \
    for (int nf = 0; nf < 4; ++nf) {                                                    \
        bfr[nf].h[0] = *(const i32x4*)(bp_ + (size_t)nf * 16 * D);                      \
        bfr[nf].h[1] = *(const i32x4*)(bp_ + (size_t)nf * 16 * D + 64);                 \
    }                                                                                   \
} while (0)

#define ITER(CUR, T, VN, DOSTAGE) do {                                                  \
    asm volatile("s_waitcnt vmcnt(" #VN ")" ::: "memory");                              \
    __builtin_amdgcn_s_barrier();                                                       \
    __builtin_amdgcn_sched_barrier(0);                                                  \
    Frag bfr[4];                                                                        \
    LOADB(T);                                                                           \
    __builtin_amdgcn_s_setprio(1);                                                      \
    _Pragma("unroll")                                                                   \
    for (int mf = 0; mf < 4; ++mf) {                                                    \
        Frag a8;                                                                        \
        LDFRAG_A(a8, CUR, wr * 64 + mf * 16 + lr);                                      \
        _Pragma("unroll")                                                               \
        for (int nf = 0; nf < 4; ++nf)                                                  \
            acc[mf][nf] = __builtin_amdgcn_mfma_scale_f32_16x16x128_f8f6f4(             \
                a8.v, bfr[nf].v, acc[mf][nf], 0, 0, 0, 0x7F7F7F7F, 0, 0x7F7F7F7F);      \
    }                                                                                   \
    __builtin_amdgcn_s_setprio(0);                                                      \
    asm volatile("s_waitcnt lgkmcnt(0)" ::: "memory");                                  \
    __builtin_amdgcn_sched_barrier(0);                                                  \
    __builtin_amdgcn_s_barrier();                                                       \
    __builtin_amdgcn_sched_barrier(0);                                                  \
    if (DOSTAGE) STAGE_A(CUR, (T) + 2);                                                 \
} while (0)

    // prologue: A tiles 0 and 1 in flight (8 outstanding vmem/wave)
    STAGE_A(0, 0);
    STAGE_A(1, 1);

    ITER(0, 0, 4, 1);   // stages A_2
    ITER(1, 1, 4, 1);   // stages A_3
    ITER(0, 2, 4, 1);   // stages A_4
    ITER(1, 3, 4, 1);   // stages A_5
    ITER(0, 4, 4, 0);   // A_5 still in flight
    ITER(1, 5, 0, 0);   // final drain
#undef ITER
#undef LOADB
#undef LDFRAG_A
#undef STAGE_A

    // C/D layout (shape-determined, = 16x16 bf16: col = lane&15, row = hi*4+reg)
    const int rifb = hi * 4;

    // diagonal capture: s_jj lives in frags (m,m) of waves with wr==wc
    if (bRow == bCol && wr == wc) {
        #pragma unroll
        for (int mf = 0; mf < 4; ++mf)
            #pragma unroll
            for (int reg = 0; reg < 4; ++reg)
                if (lr == rifb + reg)
                    diagS[bRow * 128 + wr * 64 + mf * 16 + rifb + reg] = acc[mf][mf][reg];
    }

    // last-column capture: col N-1 -> bCol==31, wc==1, nf==3, lr==15
    if (bCol == (N / 128 - 1) && wc == 1 && lr == 15) {
        #pragma unroll
        for (int mf = 0; mf < 4; ++mf)
            #pragma unroll
            for (int reg = 0; reg < 4; ++reg)
                lastS[bRow * 128 + wr * 64 + mf * 16 + rifb + reg] = acc[mf][3][reg];
    }

    // 2^s over the tile, row-sum across the wave's 64 columns
    #pragma unroll
    for (int mf = 0; mf < 4; ++mf) {
        #pragma unroll
        for (int reg = 0; reg < 4; ++reg) {
            float s = EXP2F(acc[mf][0][reg]) + EXP2F(acc[mf][1][reg]) +
                      EXP2F(acc[mf][2][reg]) + EXP2F(acc[mf][3][reg]);
            s += __shfl_xor(s, 1);
            s += __shfl_xor(s, 2);
            s += __shfl_xor(s, 4);
            s += __shfl_xor(s, 8);
            if (lr == 0) rowsum2[wc][wr * 64 + mf * 16 + rifb + reg] = s;
        }
    }
    __syncthreads();
    if (t < 128) partial[(size_t)bCol * N + bRow * 128 + t] = rowsum2[0][t] + rowsum2[1][t];
}

// rowloss + final merged: per-block sum -> one atomicAdd (out zeroed in convert)
__global__ void rowloss_kernel(const float* __restrict__ partial, const float* __restrict__ diagS,
                               const float* __restrict__ lastS, float* __restrict__ out) {
    const int j = blockIdx.x * 128 + threadIdx.x;
    float rs = 0.0f;
    #pragma unroll
    for (int tI = 0; tI < 32; ++tI) rs += partial[(size_t)tI * N + j];
    float denom = rs + EXP2F(diagS[j]);
    float lossj = LN2 * (LOG2F(denom) - lastS[j]);
    #pragma unroll
    for (int off = 1; off < 64; off <<= 1) lossj += __shfl_xor(lossj, off);
    __shared__ float ws2[2];
    if ((threadIdx.x & 63) == 0) ws2[threadIdx.x >> 6] = lossj;
    __syncthreads();
    if (threadIdx.x == 0) atomicAdd(out, ws2[0] + ws2[1]);
}

extern "C" void kernel_launch(void* const* d_in, const int* in_sizes, int n_in,
                              void* d_out, int out_size, void* d_ws, size_t ws_size,
                              hipStream_t stream) {
    const float* A = (const float*)d_in[0];
    const float* B = (const float*)d_in[1];
    float* out = (float*)d_out;
    char* ws = (char*)d_ws;

    unsigned char* Af8 = (unsigned char*)(ws);
    unsigned char* Bf8 = (unsigned char*)(ws + 3145728);
    float* partial     = (float*)(ws + 6291456);
    float* diagS       = (float*)(ws + 6815744);
    float* lastS       = (float*)(ws + 6832128);

    convert_kernel<<<1024, 256, 0, stream>>>(A, B, (unsigned*)Af8, (unsigned*)Bf8, out);
    gemm_kernel<<<1024, 256, 0, stream>>>(Af8, Bf8, partial, diagS, lastS);
    rowloss_kernel<<<32, 128, 0, stream>>>(partial, diagS, lastS, out);
}

// Round 13
// 34.119 us; speedup vs baseline: 1.4236x; 1.4236x over previous
//
#include <hip/hip_runtime.h>
#include <hip/hip_bf16.h>

#define N 4096
#define D 768
#define LN2 0.69314718055994530942f
#define QSCALE 5.371583f   // sqrt(20 * log2(e)); applied to BOTH inputs -> logits in base-2 domain

typedef __attribute__((ext_vector_type(4))) int   i32x4;
typedef __attribute__((ext_vector_type(8))) int   i32x8;
typedef __attribute__((ext_vector_type(4))) float f32x4;

#define EXP2F(x) __builtin_amdgcn_exp2f(x)   // v_exp_f32: 2^x
#define LOG2F(x) __builtin_amdgcn_logf(x)    // v_log_f32: log2(x)

// global -> LDS direct DMA, 16B per lane, linear dest (wave base + lane*16)
#define GLDS16(g, l) __builtin_amdgcn_global_load_lds( \
    (const __attribute__((address_space(1))) void*)(g), \
    (__attribute__((address_space(3))) void*)(l), 16, 0, 0)

// ws layout (bytes):
//   [0,       3145728)  A fp8 e4m3 (anchors * QSCALE), N*D
//   [3145728, 6291456)  B fp8 e4m3 (positives * QSCALE), N*D
//   [6291456, 6815744)  partial[32][4096] float  (per colTile row sums of 2^s)
//   [6815744, 6832128)  diagS[4096] float        (s2_jj, base-2 logit)
//   [6832128, 6848512)  lastS[4096] float        (s2_{j,N-1})

__global__ void convert_kernel(const float* __restrict__ A, const float* __restrict__ B,
                               unsigned* __restrict__ Af8, unsigned* __restrict__ Bf8,
                               float* __restrict__ out) {
    if (blockIdx.x == 0 && threadIdx.x == 0) out[0] = 0.0f;  // rowloss atomicAdd target
    const int total = N * D / 4;
    int idx = blockIdx.x * blockDim.x + threadIdx.x;
    int stride = gridDim.x * blockDim.x;
    for (int i = idx; i < total; i += stride) {
        float4 a = ((const float4*)A)[i];
        float4 b = ((const float4*)B)[i];
        int pa = __builtin_amdgcn_cvt_pk_fp8_f32(a.x * QSCALE, a.y * QSCALE, 0, 0);
        pa     = __builtin_amdgcn_cvt_pk_fp8_f32(a.z * QSCALE, a.w * QSCALE, pa, 1);
        int pb = __builtin_amdgcn_cvt_pk_fp8_f32(b.x * QSCALE, b.y * QSCALE, 0, 0);
        pb     = __builtin_amdgcn_cvt_pk_fp8_f32(b.z * QSCALE, b.w * QSCALE, pb, 1);
        Af8[i] = (unsigned)pa;
        Bf8[i] = (unsigned)pb;
    }
}

// 128x128 tile, BK=128, 4 waves (2x2), per-wave 64x64 = acc[4][4] of
// 16x16x128 scaled-MFMA (scales = 1.0 = 0x7F E8M0) — the verified R9/R11
// compute core, with ONE structural change vs R11:
// SINGLE-buffered LDS (A 16 KB + B 16 KB + rowsum 1 KB = 33 KB/block), so
// 4 blocks/CU (16 waves) fit instead of 2 (8 waves). The double-buffer's
// intra-block latency hiding was worth ~2 us in this lockstep structure
// (R4/R5); cross-BLOCK overlap is the proven stall-filler (m114, m93's
// single-buffered 874 TF @ 3 blocks/CU). Per K-tile:
//   STAGE -> vmcnt(0) -> barrier -> ds_read+MFMA -> lgkmcnt(0) -> barrier
// (rule 18 on the lgkmcnt; same 2 barriers/tile as R11).
// LDS linear (global_load_lds); 16B-chunk XOR-swizzle on global source AND
// fragment ds_read (rule #21). Lane k-window = chunks {hi, hi+4}: each
// ds_read_b128 spreads 64 lanes over all 8 chunks = 2 lanes/bank = free (m136).
// XCD-chunked bijective block swizzle retained (null at 2 blocks/CU but the
// 4-block working set now approaches L2 capacity, where it should help).
__global__ __launch_bounds__(256) void gemm_kernel(const unsigned char* __restrict__ Af8,
                                                   const unsigned char* __restrict__ Bf8,
                                                   float* __restrict__ partial,
                                                   float* __restrict__ diagS,
                                                   float* __restrict__ lastS) {
    __shared__ __align__(16) unsigned char As[128 * 128];  // 16 KB
    __shared__ __align__(16) unsigned char Bs[128 * 128];  // 16 KB
    __shared__ float rowsum2[2][128];

    const int t    = threadIdx.x;
    // XCD-chunked bijective swizzle (1024 blocks, nwg%8==0): xcd = bid&7 owns
    // an 8x16 rectangle of the 32x32 block grid (panels ~2.3MB < 4MB L2).
    const int bid  = blockIdx.x;
    const int xcd  = bid & 7;
    const int ii   = bid >> 3;                        // 0..127
    const int bRow = ((xcd >> 1) << 3) + (ii >> 4);   // {0,8,16,24} + 0..7
    const int bCol = ((xcd & 1) << 4) + (ii & 15);    // {0,16} + 0..15
    const int lane = t & 63;
    const int w    = t >> 6;      // wave 0..3
    const int wr   = w >> 1;      // wave row 0..1
    const int wc   = w & 1;       // wave col 0..1
    const int lr   = lane & 15;
    const int hi   = lane >> 4;   // 0..3

    // staging: thread t covers (row t>>3 of a 32-row round, 16B chunk t&7);
    // source chunk XOR-swizzled so linear LDS holds the swizzled image
    const int srow = t >> 3;            // 0..31
    const int sc   = t & 7;             // 0..7
    const int gcv  = sc ^ (srow & 7);   // swizzled global chunk
    const size_t aOff = (size_t)(bRow * 128 + srow) * D + gcv * 16;
    const size_t bOff = (size_t)(bCol * 128 + srow) * D + gcv * 16;

    f32x4 acc[4][4] = {};
    const int NT = D / 128;  // 6

    union Frag { i32x8 v; i32x4 h[2]; };

#define LDFRAG(DST, ARRBUF, ROW) do {                                                   \
    (DST).h[0] = *(const i32x4*)&(ARRBUF)[(ROW) * 128 + ((hi ^ (lr & 7)) * 16)];        \
    (DST).h[1] = *(const i32x4*)&(ARRBUF)[(ROW) * 128 + (((hi + 4) ^ (lr & 7)) * 16)];  \
} while (0)

    for (int tt = 0; tt < NT; ++tt) {
        // stage tile tt (8 GLDS/wave; buffer free: previous compute's reads
        // were drained by lgkmcnt(0)+barrier at the end of the last iteration)
        const size_t kb = (size_t)tt * 128;
        #pragma unroll
        for (int inst = 0; inst < 4; ++inst) {
            GLDS16(Af8 + aOff + (size_t)inst * 32 * D + kb, &As[inst * 4096 + w * 1024]);
            GLDS16(Bf8 + bOff + (size_t)inst * 32 * D + kb, &Bs[inst * 4096 + w * 1024]);
        }
        asm volatile("s_waitcnt vmcnt(0)" ::: "memory");
        __builtin_amdgcn_s_barrier();
        __builtin_amdgcn_sched_barrier(0);

        Frag bfr[4];
        #pragma unroll
        for (int nf = 0; nf < 4; ++nf)
            LDFRAG(bfr[nf], Bs, wc * 64 + nf * 16 + lr);
        __builtin_amdgcn_s_setprio(1);
        #pragma unroll
        for (int mf = 0; mf < 4; ++mf) {
            Frag a8;
            LDFRAG(a8, As, wr * 64 + mf * 16 + lr);
            #pragma unroll
            for (int nf = 0; nf < 4; ++nf)
                acc[mf][nf] = __builtin_amdgcn_mfma_scale_f32_16x16x128_f8f6f4(
                    a8.v, bfr[nf].v, acc[mf][nf], 0, 0, 0, 0x7F7F7F7F, 0, 0x7F7F7F7F);
        }
        __builtin_amdgcn_s_setprio(0);
        asm volatile("s_waitcnt lgkmcnt(0)" ::: "memory");
        __builtin_amdgcn_sched_barrier(0);
        __builtin_amdgcn_s_barrier();
        __builtin_amdgcn_sched_barrier(0);
    }
#undef LDFRAG

    // C/D layout (shape-determined, = 16x16 bf16: col = lane&15, row = hi*4+reg)
    const int rifb = hi * 4;

    // diagonal capture: s_jj lives in frags (m,m) of waves with wr==wc
    if (bRow == bCol && wr == wc) {
        #pragma unroll
        for (int mf = 0; mf < 4; ++mf)
            #pragma unroll
            for (int reg = 0; reg < 4; ++reg)
                if (lr == rifb + reg)
                    diagS[bRow * 128 + wr * 64 + mf * 16 + rifb + reg] = acc[mf][mf][reg];
    }

    // last-column capture: col N-1 -> bCol==31, wc==1, nf==3, lr==15
    if (bCol == (N / 128 - 1) && wc == 1 && lr == 15) {
        #pragma unroll
        for (int mf = 0; mf < 4; ++mf)
            #pragma unroll
            for (int reg = 0; reg < 4; ++reg)
                lastS[bRow * 128 + wr * 64 + mf * 16 + rifb + reg] = acc[mf][3][reg];
    }

    // 2^s over the tile, row-sum across the wave's 64 columns
    #pragma unroll
    for (int mf = 0; mf < 4; ++mf) {
        #pragma unroll
        for (int reg = 0; reg < 4; ++reg) {
            float s = EXP2F(acc[mf][0][reg]) + EXP2F(acc[mf][1][reg]) +
                      EXP2F(acc[mf][2][reg]) + EXP2F(acc[mf][3][reg]);
            s += __shfl_xor(s, 1);
            s += __shfl_xor(s, 2);
            s += __shfl_xor(s, 4);
            s += __shfl_xor(s, 8);
            if (lr == 0) rowsum2[wc][wr * 64 + mf * 16 + rifb + reg] = s;
        }
    }
    __syncthreads();
    if (t < 128) partial[(size_t)bCol * N + bRow * 128 + t] = rowsum2[0][t] + rowsum2[1][t];
}

// rowloss + final merged: per-block sum -> one atomicAdd (out zeroed in convert)
__global__ void rowloss_kernel(const float* __restrict__ partial, const float* __restrict__ diagS,
                               const float* __restrict__ lastS, float* __restrict__ out) {
    const int j = blockIdx.x * 128 + threadIdx.x;
    float rs = 0.0f;
    #pragma unroll
    for (int tI = 0; tI < 32; ++tI) rs += partial[(size_t)tI * N + j];
    float denom = rs + EXP2F(diagS[j]);
    float lossj = LN2 * (LOG2F(denom) - lastS[j]);
    #pragma unroll
    for (int off = 1; off < 64; off <<= 1) lossj += __shfl_xor(lossj, off);
    __shared__ float ws2[2];
    if ((threadIdx.x & 63) == 0) ws2[threadIdx.x >> 6] = lossj;
    __syncthreads();
    if (threadIdx.x == 0) atomicAdd(out, ws2[0] + ws2[1]);
}

extern "C" void kernel_launch(void* const* d_in, const int* in_sizes, int n_in,
                              void* d_out, int out_size, void* d_ws, size_t ws_size,
                              hipStream_t stream) {
    const float* A = (const float*)d_in[0];
    const float* B = (const float*)d_in[1];
    float* out = (float*)d_out;
    char* ws = (char*)d_ws;

    unsigned char* Af8 = (unsigned char*)(ws);
    unsigned char* Bf8 = (unsigned char*)(ws + 3145728);
    float* partial     = (float*)(ws + 6291456);
    float* diagS       = (float*)(ws + 6815744);
    float* lastS       = (float*)(ws + 6832128);

    convert_kernel<<<1024, 256, 0, stream>>>(A, B, (unsigned*)Af8, (unsigned*)Bf8, out);
    gemm_kernel<<<1024, 256, 0, stream>>>(Af8, Bf8, partial, diagS, lastS);
    rowloss_kernel<<<32, 128, 0, stream>>>(partial, diagS, lastS, out);
}